// Round 6
// baseline (245.172 us; speedup 1.0000x reference)
//
#include <hip/hip_runtime.h>
#include <hip/hip_bf16.h>
#include <stdint.h>

#define NTOT  8192
#define DIM   512
#define NI    8
#define NWAYS 1024
#define TILE  128
#define NSYM  2080   /* 64*65/2 upper-triangle tile pairs */
#define NBLK  2592   /* NSYM + 512 proto blocks = 8 * 324 */
#define MARGINV 0.3f

typedef float f32x4 __attribute__((ext_vector_type(4)));

// order-preserving float<->uint map (monotonic for all finite floats +/- inf)
__device__ __forceinline__ unsigned f2o(float f) {
  unsigned u = __float_as_uint(f);
  return (u & 0x80000000u) ? ~u : (u | 0x80000000u);
}
__device__ __forceinline__ float o2f(unsigned u) {
  u = (u & 0x80000000u) ? (u & 0x7fffffffu) : ~u;
  return __uint_as_float(u);
}

__device__ __forceinline__ float wave_sum64(float v) {
#pragma unroll
  for (int s = 32; s; s >>= 1) v += __shfl_xor(v, s, 64);
  return v;
}

// ---- prep: sq-norms + fp8(e4m3) cast + accumulator init; protos in tail ----
__global__ __launch_bounds__(256) void prep(
    const float* __restrict__ A, float* __restrict__ sq,
    float* __restrict__ psq, unsigned char* __restrict__ A8,
    unsigned char* __restrict__ P8,
    unsigned* __restrict__ an_u32, unsigned* __restrict__ ap_u32,
    unsigned long long* __restrict__ pr_key) {
  const int w = threadIdx.x >> 6;
  const int l = threadIdx.x & 63;
  const int b = blockIdx.x;
  if (b < NTOT / 4) {
    const int row = b * 4 + w;
    const float4* rp = (const float4*)(A + (size_t)row * DIM);
    unsigned* op = (unsigned*)(A8 + (size_t)row * DIM);
    float s = 0.f;
#pragma unroll
    for (int m = 0; m < 2; ++m) {
      const float4 v = rp[l + 64 * m];
      s = fmaf(v.x, v.x, fmaf(v.y, v.y, fmaf(v.z, v.z, fmaf(v.w, v.w, s))));
      int wd = 0;
      wd = __builtin_amdgcn_cvt_pk_fp8_f32(v.x, v.y, wd, false);
      wd = __builtin_amdgcn_cvt_pk_fp8_f32(v.z, v.w, wd, true);
      op[l + 64 * m] = (unsigned)wd;
    }
    s = wave_sum64(s);
    if (l == 0) {
      sq[row] = s;
      an_u32[row] = ~0u;
      ap_u32[row] = 0u;
      pr_key[row] = ~0ull;
    }
  } else {
    const int c = (b - NTOT / 4) * 4 + w;  // proto id
    unsigned* op = (unsigned*)(P8 + (size_t)c * DIM);
    float s = 0.f;
#pragma unroll
    for (int m = 0; m < 2; ++m) {
      float4 p = {0.f, 0.f, 0.f, 0.f};
#pragma unroll
      for (int r = 0; r < NI; ++r) {
        const float4 v =
            ((const float4*)(A + (size_t)(c * NI + r) * DIM))[l + 64 * m];
        p.x += v.x; p.y += v.y; p.z += v.z; p.w += v.w;
      }
      p.x *= (1.f / NI); p.y *= (1.f / NI); p.z *= (1.f / NI); p.w *= (1.f / NI);
      s = fmaf(p.x, p.x, fmaf(p.y, p.y, fmaf(p.z, p.z, fmaf(p.w, p.w, s))));
      int wd = 0;
      wd = __builtin_amdgcn_cvt_pk_fp8_f32(p.x, p.y, wd, false);
      wd = __builtin_amdgcn_cvt_pk_fp8_f32(p.z, p.w, wd, true);
      op[l + 64 * m] = (unsigned)wd;
    }
    s = wave_sum64(s);
    if (l == 0) psq[c] = s;
  }
}

// ---- fused symmetric fp8 GEMM + min/max epilogues, NO-LDS K-loop ----
// Fragments load directly global->VGPR (global_load_dwordx2); working set is
// L2-resident so LDS staging only added barrier/vmcnt-drain stalls. No
// __syncthreads in the K-loop; one barrier before the cross-wave combine.
__global__ __launch_bounds__(256, 4) void gemm_fused(
    const unsigned char* __restrict__ A, const unsigned char* __restrict__ P,
    const float* __restrict__ sq, const float* __restrict__ psq,
    unsigned* __restrict__ an_u32, unsigned* __restrict__ ap_u32,
    unsigned long long* __restrict__ pr_key) {
  __shared__ float rminL[TILE][2];
  __shared__ float cminL[TILE][2];
  __shared__ float amaxL[TILE][2];
  __shared__ unsigned long long rowkey[TILE][2];  // proto path only

  const int braw = blockIdx.x;
  const int b = (braw & 7) * (NBLK / 8) + (braw >> 3);  // XCD-contiguous
  const bool isProto = b >= NSYM;
  int bi, bj;
  const unsigned char* Bmat;
  const float* sqB;
  if (!isProto) {
    // supertile decode: pairs (Si<=Sj) of 8x8-tile supertiles
    int rem = b, Si = 0, Sj = 0;
    for (;;) {
      const int cnt = (Si == Sj) ? 36 : 64;
      if (rem < cnt) break;
      rem -= cnt;
      ++Si;
      if (Si > Sj) { Si = 0; ++Sj; }
    }
    int bi_l, bj_l;
    if (Si == Sj) {
      bj_l = 0;
      while ((bj_l + 1) * (bj_l + 2) / 2 <= rem) ++bj_l;
      bi_l = rem - bj_l * (bj_l + 1) / 2;
    } else {
      bi_l = rem & 7;
      bj_l = rem >> 3;
    }
    bi = Si * 8 + bi_l;
    bj = Sj * 8 + bj_l;
    Bmat = A;
    sqB = sq;
  } else {
    const int p = b - NSYM;
    bj = p & 7;
    bi = p >> 3;
    Bmat = P;
    sqB = psq;
  }
  const int rowBase = bi * TILE;
  const int colBase = bj * TILE;
  const bool isDiag = !isProto && (bi == bj);
  const bool colSide = !isProto && (bi != bj);

  const int t = threadIdx.x;
  const int lane = t & 63;
  const int wv = t >> 6;
  const int wr = wv >> 1;
  const int wc = wv & 1;
  const int quad = lane >> 4;
  const int lc = lane & 15;

  // per-lane fragment base pointers: A row = rowBase+wr*64+x*16+lc, k = quad*8
  const unsigned char* pA[4];
  const unsigned char* pB[4];
#pragma unroll
  for (int x = 0; x < 4; ++x) {
    pA[x] = A + (size_t)(rowBase + wr * 64 + x * 16 + lc) * DIM + quad * 8;
    pB[x] = Bmat + (size_t)(colBase + wc * 64 + x * 16 + lc) * DIM + quad * 8;
  }

  f32x4 acc[4][4] = {};
  long af[2][4], bf[2][4];

  // prefetch chunk 0
#pragma unroll
  for (int x = 0; x < 4; ++x) {
    af[0][x] = *(const long*)(pA[x]);
    bf[0][x] = *(const long*)(pB[x]);
  }
  // 16 chunks of k=32, pipelined one chunk ahead; no barriers, no LDS
#pragma unroll
  for (int ch = 0; ch < 16; ++ch) {
    const int cur = ch & 1, nxt = cur ^ 1;
    if (ch < 15) {
      const int ko = (ch + 1) * 32;
#pragma unroll
      for (int x = 0; x < 4; ++x) {
        af[nxt][x] = *(const long*)(pA[x] + ko);
        bf[nxt][x] = *(const long*)(pB[x] + ko);
      }
    }
#pragma unroll
    for (int x = 0; x < 4; ++x)
#pragma unroll
      for (int y = 0; y < 4; ++y)
        acc[x][y] = __builtin_amdgcn_mfma_f32_16x16x32_fp8_fp8(
            af[cur][x], bf[cur][y], acc[x][y], 0, 0, 0);
  }

  // ---- epilogue. C/D layout: col=lane&15, row=quad*4+reg ----
  float sb[4];
#pragma unroll
  for (int y = 0; y < 4; ++y) sb[y] = sqB[colBase + wc * 64 + y * 16 + lc];

  const float INF = __int_as_float(0x7f800000);

  if (!isProto) {
    // row-side: min over y per lane, butterfly over lc (strides 1..8),
    // single-writer LDS store (no atomics, no init).
#pragma unroll
    for (int x = 0; x < 4; ++x) {
#pragma unroll
      for (int r = 0; r < 4; ++r) {
        const int rloc = wr * 64 + x * 16 + quad * 4 + r;
        float mv = INF, mx = -INF;
#pragma unroll
        for (int y = 0; y < 4; ++y) {
          const float v = fmaf(-2.f, acc[x][y][r], sb[y]);
          if (isDiag) {
            const int col = colBase + wc * 64 + y * 16 + lc;
            const bool same = ((rowBase + rloc) >> 3) == (col >> 3);
            mv = fminf(mv, same ? INF : v);
            mx = fmaxf(mx, same ? v : -INF);
          } else {
            mv = fminf(mv, v);
          }
        }
#pragma unroll
        for (int s = 1; s < 16; s <<= 1) mv = fminf(mv, __shfl_xor(mv, s, 64));
        if (isDiag) {
#pragma unroll
          for (int s = 1; s < 16; s <<= 1) mx = fmaxf(mx, __shfl_xor(mx, s, 64));
        }
        if (lc == 0) {
          rminL[rloc][wc] = mv;
          if (isDiag) amaxL[rloc][wc] = mx;
        }
      }
    }
    // col-side (off-diag): min over (x,r) per y, butterfly over quad
    if (colSide) {
      float sa[4][4];
#pragma unroll
      for (int x = 0; x < 4; ++x)
#pragma unroll
        for (int r = 0; r < 4; ++r)
          sa[x][r] = sq[rowBase + wr * 64 + x * 16 + quad * 4 + r];
#pragma unroll
      for (int y = 0; y < 4; ++y) {
        float cv = INF;
#pragma unroll
        for (int x = 0; x < 4; ++x)
#pragma unroll
          for (int r = 0; r < 4; ++r)
            cv = fminf(cv, fmaf(-2.f, acc[x][y][r], sa[x][r]));
#pragma unroll
        for (int s = 16; s < 64; s <<= 1) cv = fminf(cv, __shfl_xor(cv, s, 64));
        if (quad == 0) cminL[wc * 64 + y * 16 + lc][wr] = cv;
      }
    }
  } else {
    // proto path: need argmin index -> u64 keys + 16-lane butterfly
#pragma unroll
    for (int x = 0; x < 4; ++x) {
      unsigned long long kmin[4] = {~0ull, ~0ull, ~0ull, ~0ull};
#pragma unroll
      for (int y = 0; y < 4; ++y) {
        const int col = colBase + wc * 64 + y * 16 + lc;
#pragma unroll
        for (int r = 0; r < 4; ++r) {
          const float v = fmaf(-2.f, acc[x][y][r], sb[y]);
          const unsigned long long kn =
              ((unsigned long long)f2o(v) << 32) | (unsigned)col;
          if (kn < kmin[r]) kmin[r] = kn;
        }
      }
#pragma unroll
      for (int r = 0; r < 4; ++r) {
#pragma unroll
        for (int s = 1; s < 16; s <<= 1) {
          const unsigned long long o = __shfl_xor(kmin[r], s, 64);
          if (o < kmin[r]) kmin[r] = o;
        }
      }
      if (lc == 0) {
#pragma unroll
        for (int r = 0; r < 4; ++r)
          rowkey[wr * 64 + x * 16 + quad * 4 + r][wc] = kmin[r];
      }
    }
  }

  __syncthreads();
  if (isProto) {
    if (t < TILE) {
      unsigned long long a = rowkey[t][0];
      const unsigned long long c = rowkey[t][1];
      if (c < a) a = c;
      atomicMin(pr_key + rowBase + t, a);
    }
  } else {
    if (t < TILE) {
      atomicMin(an_u32 + rowBase + t, f2o(fminf(rminL[t][0], rminL[t][1])));
    } else if (t < 2 * TILE) {
      const int i = t - TILE;
      if (colSide)
        atomicMin(an_u32 + colBase + i, f2o(fminf(cminL[i][0], cminL[i][1])));
      else if (isDiag)
        atomicMax(ap_u32 + rowBase + i, f2o(fmaxf(amaxL[i][0], amaxL[i][1])));
    }
  }
}

// ---- final scalar reductions ----
__global__ void finalize_kernel(const float* __restrict__ sq,
                                const unsigned* __restrict__ an_u32,
                                const unsigned* __restrict__ ap_u32,
                                const unsigned long long* __restrict__ pr_key,
                                float* __restrict__ out) {
  const int tid = threadIdx.x;  // 1024 threads
  float loss = 0.f, sp = 0.f, sn = 0.f, acc = 0.f;
#pragma unroll
  for (int i = tid; i < NTOT; i += 1024) {
    const float s = sq[i];
    const float ap = sqrtf(fmaxf(s + o2f(ap_u32[i]), 1e-12f));
    const float an = sqrtf(fmaxf(s + o2f(an_u32[i]), 1e-12f));
    loss += fmaxf(ap - an + MARGINV, 0.f);
    sp += ap;
    sn += an;
    acc += ((unsigned)(pr_key[i] & 0xffffffffu) == (unsigned)(i >> 3)) ? 1.f : 0.f;
  }
  loss = wave_sum64(loss);
  sp = wave_sum64(sp);
  sn = wave_sum64(sn);
  acc = wave_sum64(acc);
  __shared__ float red[16][4];
  const int w = tid >> 6, l = tid & 63;
  if (l == 0) { red[w][0] = loss; red[w][1] = acc; red[w][2] = sp; red[w][3] = sn; }
  __syncthreads();
  if (tid == 0) {
    float L = 0, Ac = 0, Pm = 0, Nn = 0;
    for (int i = 0; i < 16; ++i) {
      L += red[i][0]; Ac += red[i][1]; Pm += red[i][2]; Nn += red[i][3];
    }
    out[0] = L / NTOT;   // W = 1.0
    out[1] = Ac / NTOT;
    out[2] = Pm / NTOT;
    out[3] = Nn / NTOT;
  }
}

extern "C" void kernel_launch(void* const* d_in, const int* in_sizes, int n_in,
                              void* d_out, int out_size, void* d_ws, size_t ws_size,
                              hipStream_t stream) {
  const float* inputs = (const float*)d_in[0];
  float* out = (float*)d_out;
  char* w = (char*)d_ws;
  float* sq  = (float*)(w);                                       // 32 KB
  float* psq = (float*)(w + 32768);                               // 4 KB
  unsigned* an_u32 = (unsigned*)(w + 36864);                      // 32 KB
  unsigned* ap_u32 = (unsigned*)(w + 69632);                      // 32 KB
  unsigned long long* pr_key = (unsigned long long*)(w + 102400); // 64 KB
  unsigned char* A8 = (unsigned char*)(w + 167936);               // 4 MB
  unsigned char* P8 = (unsigned char*)(w + 167936 + (size_t)NTOT * DIM);

  prep<<<NTOT / 4 + NWAYS / 4, 256, 0, stream>>>(inputs, sq, psq, A8, P8,
                                                 an_u32, ap_u32, pr_key);
  gemm_fused<<<NBLK, 256, 0, stream>>>(A8, P8, sq, psq,
                                       an_u32, ap_u32, pr_key);
  finalize_kernel<<<1, 1024, 0, stream>>>(sq, an_u32, ap_u32, pr_key, out);
}

// Round 7
// 179.168 us; speedup vs baseline: 1.3684x; 1.3684x over previous
//
#include <hip/hip_runtime.h>
#include <hip/hip_bf16.h>
#include <stdint.h>

#define NTOT  8192
#define DIM   512
#define NI    8
#define NWAYS 1024
#define TILE  128
#define NSYM  2080   /* 64*65/2 upper-triangle tile pairs */
#define NBLK  2592   /* NSYM + 512 proto blocks = 8 * 324 */
#define MARGINV 0.3f

typedef float f32x4 __attribute__((ext_vector_type(4)));

// order-preserving float<->uint map (monotonic for all finite floats +/- inf)
__device__ __forceinline__ unsigned f2o(float f) {
  unsigned u = __float_as_uint(f);
  return (u & 0x80000000u) ? ~u : (u | 0x80000000u);
}
__device__ __forceinline__ float o2f(unsigned u) {
  u = (u & 0x80000000u) ? (u & 0x7fffffffu) : ~u;
  return __uint_as_float(u);
}

__device__ __forceinline__ float wave_sum64(float v) {
#pragma unroll
  for (int s = 32; s; s >>= 1) v += __shfl_xor(v, s, 64);
  return v;
}

__device__ __forceinline__ unsigned dev_load_u32(const unsigned* p) {
  return __hip_atomic_load(p, __ATOMIC_RELAXED, __HIP_MEMORY_SCOPE_AGENT);
}
__device__ __forceinline__ unsigned long long dev_load_u64(
    const unsigned long long* p) {
  return __hip_atomic_load(p, __ATOMIC_RELAXED, __HIP_MEMORY_SCOPE_AGENT);
}

// Fragment-native permuted fp8 layout:
//   off(row,k) = (row>>4)*8192 + (k>>5)*512 + ((k>>3)&3)*128 + (row&15)*8 + (k&7)
// A wave's MFMA fragment (16 rows x 32 k) is 512 contiguous bytes at
// base + lane*8 -> fully coalesced global_load_dwordx2, no LDS needed.

// ---- prep: sq-norms + fp8(e4m3) cast into PERMUTED layout + init ----
__global__ __launch_bounds__(256) void prep(
    const float* __restrict__ A, float* __restrict__ sq,
    float* __restrict__ psq, unsigned char* __restrict__ A8,
    unsigned char* __restrict__ P8,
    unsigned* __restrict__ an_u32, unsigned* __restrict__ ap_u32,
    unsigned long long* __restrict__ pr_key, unsigned* __restrict__ cnt) {
  if (blockIdx.x == 0 && threadIdx.x == 0) *cnt = 0;
  const int w = threadIdx.x >> 6;
  const int l = threadIdx.x & 63;
  const int b = blockIdx.x;
  if (b < NTOT / 4) {
    const int row = b * 4 + w;
    const float4* rp = (const float4*)(A + (size_t)row * DIM);
    const size_t rb = ((size_t)(row >> 4) << 13) + ((row & 15) << 3);
    float s = 0.f;
#pragma unroll
    for (int m = 0; m < 2; ++m) {
      const int k0 = (l + 64 * m) * 4;
      const float4 v = rp[l + 64 * m];
      s = fmaf(v.x, v.x, fmaf(v.y, v.y, fmaf(v.z, v.z, fmaf(v.w, v.w, s))));
      int wd = 0;
      wd = __builtin_amdgcn_cvt_pk_fp8_f32(v.x, v.y, wd, false);
      wd = __builtin_amdgcn_cvt_pk_fp8_f32(v.z, v.w, wd, true);
      const size_t off = rb + ((k0 >> 5) << 9) + (((k0 >> 3) & 3) << 7) + (k0 & 7);
      *(unsigned*)(A8 + off) = (unsigned)wd;
    }
    s = wave_sum64(s);
    if (l == 0) {
      sq[row] = s;
      an_u32[row] = ~0u;
      ap_u32[row] = 0u;
      pr_key[row] = ~0ull;
    }
  } else {
    const int c = (b - NTOT / 4) * 4 + w;  // proto id
    const size_t rb = ((size_t)(c >> 4) << 13) + ((c & 15) << 3);
    float s = 0.f;
#pragma unroll
    for (int m = 0; m < 2; ++m) {
      const int k0 = (l + 64 * m) * 4;
      float4 p = {0.f, 0.f, 0.f, 0.f};
#pragma unroll
      for (int r = 0; r < NI; ++r) {
        const float4 v =
            ((const float4*)(A + (size_t)(c * NI + r) * DIM))[l + 64 * m];
        p.x += v.x; p.y += v.y; p.z += v.z; p.w += v.w;
      }
      p.x *= (1.f / NI); p.y *= (1.f / NI); p.z *= (1.f / NI); p.w *= (1.f / NI);
      s = fmaf(p.x, p.x, fmaf(p.y, p.y, fmaf(p.z, p.z, fmaf(p.w, p.w, s))));
      int wd = 0;
      wd = __builtin_amdgcn_cvt_pk_fp8_f32(p.x, p.y, wd, false);
      wd = __builtin_amdgcn_cvt_pk_fp8_f32(p.z, p.w, wd, true);
      const size_t off = rb + ((k0 >> 5) << 9) + (((k0 >> 3) & 3) << 7) + (k0 & 7);
      *(unsigned*)(P8 + off) = (unsigned)wd;
    }
    s = wave_sum64(s);
    if (l == 0) psq[c] = s;
  }
}

// ---- fused symmetric fp8 GEMM + min/max epilogues + last-block finalize ----
// No-LDS K-loop: coalesced global->VGPR fragment loads from permuted layout,
// no barriers in the loop. Epilogue via shuffles + single-writer LDS.
__global__ __launch_bounds__(256, 4) void gemm_fused(
    const unsigned char* __restrict__ A, const unsigned char* __restrict__ P,
    const float* __restrict__ sq, const float* __restrict__ psq,
    unsigned* __restrict__ an_u32, unsigned* __restrict__ ap_u32,
    unsigned long long* __restrict__ pr_key, unsigned* __restrict__ cnt,
    float* __restrict__ out) {
  __shared__ float rminL[TILE][2];
  __shared__ float cminL[TILE][2];
  __shared__ float amaxL[TILE][2];
  __shared__ unsigned long long rowkey[TILE][2];  // proto path only
  __shared__ int lastFlag;
  __shared__ float red2[4][4];

  const int braw = blockIdx.x;
  const int b = (braw & 7) * (NBLK / 8) + (braw >> 3);  // XCD-contiguous
  const bool isProto = b >= NSYM;
  int bi, bj;
  const unsigned char* Bmat;
  const float* sqB;
  if (!isProto) {
    // supertile decode: pairs (Si<=Sj) of 8x8-tile supertiles
    int rem = b, Si = 0, Sj = 0;
    for (;;) {
      const int cnt2 = (Si == Sj) ? 36 : 64;
      if (rem < cnt2) break;
      rem -= cnt2;
      ++Si;
      if (Si > Sj) { Si = 0; ++Sj; }
    }
    int bi_l, bj_l;
    if (Si == Sj) {
      bj_l = 0;
      while ((bj_l + 1) * (bj_l + 2) / 2 <= rem) ++bj_l;
      bi_l = rem - bj_l * (bj_l + 1) / 2;
    } else {
      bi_l = rem & 7;
      bj_l = rem >> 3;
    }
    bi = Si * 8 + bi_l;
    bj = Sj * 8 + bj_l;
    Bmat = A;
    sqB = sq;
  } else {
    const int p = b - NSYM;
    bj = p & 7;
    bi = p >> 3;
    Bmat = P;
    sqB = psq;
  }
  const int rowBase = bi * TILE;
  const int colBase = bj * TILE;
  const bool isDiag = !isProto && (bi == bj);
  const bool colSide = !isProto && (bi != bj);

  const int t = threadIdx.x;
  const int lane = t & 63;
  const int wv = t >> 6;
  const int wr = wv >> 1;
  const int wc = wv & 1;
  const int quad = lane >> 4;
  const int lc = lane & 15;

  // permuted-layout fragment pointers: 512 B per (row-group, chunk), dense
  const unsigned char* pA[4];
  const unsigned char* pB[4];
#pragma unroll
  for (int x = 0; x < 4; ++x) {
    pA[x] = A + (size_t)(rowBase + wr * 64 + x * 16) * DIM + lane * 8;
    pB[x] = Bmat + (size_t)(colBase + wc * 64 + x * 16) * DIM + lane * 8;
  }

  f32x4 acc[4][4] = {};
  long af[2][4], bf[2][4];

  // prefetch chunk 0
#pragma unroll
  for (int x = 0; x < 4; ++x) {
    af[0][x] = *(const long*)(pA[x]);
    bf[0][x] = *(const long*)(pB[x]);
  }
  // 16 chunks of k=32, pipelined one chunk ahead; no barriers, no LDS
#pragma unroll
  for (int ch = 0; ch < 16; ++ch) {
    const int cur = ch & 1, nxt = cur ^ 1;
    if (ch < 15) {
      const int ko = (ch + 1) * 512;
#pragma unroll
      for (int x = 0; x < 4; ++x) {
        af[nxt][x] = *(const long*)(pA[x] + ko);
        bf[nxt][x] = *(const long*)(pB[x] + ko);
      }
    }
#pragma unroll
    for (int x = 0; x < 4; ++x)
#pragma unroll
      for (int y = 0; y < 4; ++y)
        acc[x][y] = __builtin_amdgcn_mfma_f32_16x16x32_fp8_fp8(
            af[cur][x], bf[cur][y], acc[x][y], 0, 0, 0);
  }

  // ---- epilogue. C/D layout: col=lane&15, row=quad*4+reg ----
  float sb[4];
#pragma unroll
  for (int y = 0; y < 4; ++y) sb[y] = sqB[colBase + wc * 64 + y * 16 + lc];

  const float INF = __int_as_float(0x7f800000);

  if (!isProto) {
#pragma unroll
    for (int x = 0; x < 4; ++x) {
#pragma unroll
      for (int r = 0; r < 4; ++r) {
        const int rloc = wr * 64 + x * 16 + quad * 4 + r;
        float mv = INF, mx = -INF;
#pragma unroll
        for (int y = 0; y < 4; ++y) {
          const float v = fmaf(-2.f, acc[x][y][r], sb[y]);
          if (isDiag) {
            const int col = colBase + wc * 64 + y * 16 + lc;
            const bool same = ((rowBase + rloc) >> 3) == (col >> 3);
            mv = fminf(mv, same ? INF : v);
            mx = fmaxf(mx, same ? v : -INF);
          } else {
            mv = fminf(mv, v);
          }
        }
#pragma unroll
        for (int s = 1; s < 16; s <<= 1) mv = fminf(mv, __shfl_xor(mv, s, 64));
        if (isDiag) {
#pragma unroll
          for (int s = 1; s < 16; s <<= 1) mx = fmaxf(mx, __shfl_xor(mx, s, 64));
        }
        if (lc == 0) {
          rminL[rloc][wc] = mv;
          if (isDiag) amaxL[rloc][wc] = mx;
        }
      }
    }
    if (colSide) {
      float sa[4][4];
#pragma unroll
      for (int x = 0; x < 4; ++x)
#pragma unroll
        for (int r = 0; r < 4; ++r)
          sa[x][r] = sq[rowBase + wr * 64 + x * 16 + quad * 4 + r];
#pragma unroll
      for (int y = 0; y < 4; ++y) {
        float cv = INF;
#pragma unroll
        for (int x = 0; x < 4; ++x)
#pragma unroll
          for (int r = 0; r < 4; ++r)
            cv = fminf(cv, fmaf(-2.f, acc[x][y][r], sa[x][r]));
#pragma unroll
        for (int s = 16; s < 64; s <<= 1) cv = fminf(cv, __shfl_xor(cv, s, 64));
        if (quad == 0) cminL[wc * 64 + y * 16 + lc][wr] = cv;
      }
    }
  } else {
    // proto path: need argmin index -> u64 keys + 16-lane butterfly
#pragma unroll
    for (int x = 0; x < 4; ++x) {
      unsigned long long kmin[4] = {~0ull, ~0ull, ~0ull, ~0ull};
#pragma unroll
      for (int y = 0; y < 4; ++y) {
        const int col = colBase + wc * 64 + y * 16 + lc;
#pragma unroll
        for (int r = 0; r < 4; ++r) {
          const float v = fmaf(-2.f, acc[x][y][r], sb[y]);
          const unsigned long long kn =
              ((unsigned long long)f2o(v) << 32) | (unsigned)col;
          if (kn < kmin[r]) kmin[r] = kn;
        }
      }
#pragma unroll
      for (int r = 0; r < 4; ++r) {
#pragma unroll
        for (int s = 1; s < 16; s <<= 1) {
          const unsigned long long o = __shfl_xor(kmin[r], s, 64);
          if (o < kmin[r]) kmin[r] = o;
        }
      }
      if (lc == 0) {
#pragma unroll
        for (int r = 0; r < 4; ++r)
          rowkey[wr * 64 + x * 16 + quad * 4 + r][wc] = kmin[r];
      }
    }
  }

  __syncthreads();
  if (isProto) {
    if (t < TILE) {
      unsigned long long a = rowkey[t][0];
      const unsigned long long c = rowkey[t][1];
      if (c < a) a = c;
      atomicMin(pr_key + rowBase + t, a);
    }
  } else {
    if (t < TILE) {
      atomicMin(an_u32 + rowBase + t, f2o(fminf(rminL[t][0], rminL[t][1])));
    } else if (t < 2 * TILE) {
      const int i = t - TILE;
      if (colSide)
        atomicMin(an_u32 + colBase + i, f2o(fminf(cminL[i][0], cminL[i][1])));
      else if (isDiag)
        atomicMax(ap_u32 + rowBase + i, f2o(fmaxf(amaxL[i][0], amaxL[i][1])));
    }
  }

  // ---- last-block finalize (saves one kernel dispatch) ----
  __syncthreads();  // drains this block's global atomics (vmcnt(0) before barrier)
  if (t == 0) {
    __threadfence();
    lastFlag = (atomicAdd(cnt, 1u) == NBLK - 1) ? 1 : 0;
  }
  __syncthreads();
  if (lastFlag) {
    __threadfence();
    float loss = 0.f, sp = 0.f, sn = 0.f, accv = 0.f;
#pragma unroll 8
    for (int i = t; i < NTOT; i += 256) {
      const float s = sq[i];
      const float ap = sqrtf(fmaxf(s + o2f(dev_load_u32(ap_u32 + i)), 1e-12f));
      const float an = sqrtf(fmaxf(s + o2f(dev_load_u32(an_u32 + i)), 1e-12f));
      loss += fmaxf(ap - an + MARGINV, 0.f);
      sp += ap;
      sn += an;
      accv += ((unsigned)(dev_load_u64(pr_key + i) & 0xffffffffu) ==
               (unsigned)(i >> 3)) ? 1.f : 0.f;
    }
    loss = wave_sum64(loss);
    sp = wave_sum64(sp);
    sn = wave_sum64(sn);
    accv = wave_sum64(accv);
    if (lane == 0) {
      red2[wv][0] = loss; red2[wv][1] = accv; red2[wv][2] = sp; red2[wv][3] = sn;
    }
    __syncthreads();
    if (t == 0) {
      float L = 0, Ac = 0, Pm = 0, Nn = 0;
#pragma unroll
      for (int i = 0; i < 4; ++i) {
        L += red2[i][0]; Ac += red2[i][1]; Pm += red2[i][2]; Nn += red2[i][3];
      }
      out[0] = L / NTOT;   // W = 1.0
      out[1] = Ac / NTOT;
      out[2] = Pm / NTOT;
      out[3] = Nn / NTOT;
    }
  }
}

extern "C" void kernel_launch(void* const* d_in, const int* in_sizes, int n_in,
                              void* d_out, int out_size, void* d_ws, size_t ws_size,
                              hipStream_t stream) {
  const float* inputs = (const float*)d_in[0];
  float* out = (float*)d_out;
  char* w = (char*)d_ws;
  float* sq  = (float*)(w);                                       // 32 KB
  float* psq = (float*)(w + 32768);                               // 4 KB
  unsigned* an_u32 = (unsigned*)(w + 36864);                      // 32 KB
  unsigned* ap_u32 = (unsigned*)(w + 69632);                      // 32 KB
  unsigned long long* pr_key = (unsigned long long*)(w + 102400); // 64 KB
  unsigned* cnt = (unsigned*)(w + 167936);                        // 4 B
  unsigned char* A8 = (unsigned char*)(w + 168192);               // 4 MB (permuted)
  unsigned char* P8 = (unsigned char*)(w + 168192 + (size_t)NTOT * DIM);

  prep<<<NTOT / 4 + NWAYS / 4, 256, 0, stream>>>(inputs, sq, psq, A8, P8,
                                                 an_u32, ap_u32, pr_key, cnt);
  gemm_fused<<<NBLK, 256, 0, stream>>>(A8, P8, sq, psq,
                                       an_u32, ap_u32, pr_key, cnt, out);
}

// Round 8
// 171.462 us; speedup vs baseline: 1.4299x; 1.0449x over previous
//
#include <hip/hip_runtime.h>
#include <hip/hip_bf16.h>
#include <stdint.h>

#define NTOT  8192
#define DIM   512
#define NI    8
#define NWAYS 1024
#define TILE  128
#define NSYM  2080   /* 64*65/2 upper-triangle tile pairs */
#define NBLK  2592   /* NSYM + 512 proto blocks = 8 * 324 */
#define MARGINV 0.3f

typedef float f32x4 __attribute__((ext_vector_type(4)));

// order-preserving float<->uint map (monotonic for all finite floats +/- inf)
__device__ __forceinline__ unsigned f2o(float f) {
  unsigned u = __float_as_uint(f);
  return (u & 0x80000000u) ? ~u : (u | 0x80000000u);
}
__device__ __forceinline__ float o2f(unsigned u) {
  u = (u & 0x80000000u) ? (u & 0x7fffffffu) : ~u;
  return __uint_as_float(u);
}

__device__ __forceinline__ float wave_sum64(float v) {
#pragma unroll
  for (int s = 32; s; s >>= 1) v += __shfl_xor(v, s, 64);
  return v;
}

__device__ __forceinline__ unsigned dev_load_u32(const unsigned* p) {
  return __hip_atomic_load(p, __ATOMIC_RELAXED, __HIP_MEMORY_SCOPE_AGENT);
}
__device__ __forceinline__ unsigned long long dev_load_u64(
    const unsigned long long* p) {
  return __hip_atomic_load(p, __ATOMIC_RELAXED, __HIP_MEMORY_SCOPE_AGENT);
}

__device__ __forceinline__ void async_ld16(const void* g, const void* l) {
  __builtin_amdgcn_global_load_lds(
      (__attribute__((address_space(1))) void*)(uintptr_t)g,
      (__attribute__((address_space(3))) void*)(uintptr_t)l, 16, 0, 0);
}

// Fragment-native permuted fp8 layout:
//   off(row,k) = (row>>4)*8192 + (k>>5)*512 + ((k>>3)&3)*128 + (row&15)*8 + (k&7)
// One MFMA fragment (16 rows x 32 k) = 512 contiguous bytes; lane reads at
// base + lane*8. A 128-row x 128-k tile = 8 row-groups x 2 KB contiguous.

// ---- prep: sq-norms + fp8(e4m3) cast into PERMUTED layout (nt stores) ----
__global__ __launch_bounds__(256) void prep(
    const float* __restrict__ A, float* __restrict__ sq,
    float* __restrict__ psq, unsigned char* __restrict__ A8,
    unsigned char* __restrict__ P8,
    unsigned* __restrict__ an_u32, unsigned* __restrict__ ap_u32,
    unsigned long long* __restrict__ pr_key, unsigned* __restrict__ cnt) {
  if (blockIdx.x == 0 && threadIdx.x == 0) *cnt = 0;
  const int w = threadIdx.x >> 6;
  const int l = threadIdx.x & 63;
  const int b = blockIdx.x;
  if (b < NTOT / 4) {
    const int row = b * 4 + w;
    const float4* rp = (const float4*)(A + (size_t)row * DIM);
    const size_t rb = ((size_t)(row >> 4) << 13) + ((row & 15) << 3);
    float s = 0.f;
#pragma unroll
    for (int m = 0; m < 2; ++m) {
      const int k0 = (l + 64 * m) * 4;
      const float4 v = rp[l + 64 * m];
      s = fmaf(v.x, v.x, fmaf(v.y, v.y, fmaf(v.z, v.z, fmaf(v.w, v.w, s))));
      int wd = 0;
      wd = __builtin_amdgcn_cvt_pk_fp8_f32(v.x, v.y, wd, false);
      wd = __builtin_amdgcn_cvt_pk_fp8_f32(v.z, v.w, wd, true);
      const size_t off = rb + ((k0 >> 5) << 9) + (((k0 >> 3) & 3) << 7) + (k0 & 7);
      __builtin_nontemporal_store((unsigned)wd, (unsigned*)(A8 + off));
    }
    s = wave_sum64(s);
    if (l == 0) {
      sq[row] = s;
      an_u32[row] = ~0u;
      ap_u32[row] = 0u;
      pr_key[row] = ~0ull;
    }
  } else {
    const int c = (b - NTOT / 4) * 4 + w;  // proto id
    const size_t rb = ((size_t)(c >> 4) << 13) + ((c & 15) << 3);
    float s = 0.f;
#pragma unroll
    for (int m = 0; m < 2; ++m) {
      const int k0 = (l + 64 * m) * 4;
      float4 p = {0.f, 0.f, 0.f, 0.f};
#pragma unroll
      for (int r = 0; r < NI; ++r) {
        const float4 v =
            ((const float4*)(A + (size_t)(c * NI + r) * DIM))[l + 64 * m];
        p.x += v.x; p.y += v.y; p.z += v.z; p.w += v.w;
      }
      p.x *= (1.f / NI); p.y *= (1.f / NI); p.z *= (1.f / NI); p.w *= (1.f / NI);
      s = fmaf(p.x, p.x, fmaf(p.y, p.y, fmaf(p.z, p.z, fmaf(p.w, p.w, s))));
      int wd = 0;
      wd = __builtin_amdgcn_cvt_pk_fp8_f32(p.x, p.y, wd, false);
      wd = __builtin_amdgcn_cvt_pk_fp8_f32(p.z, p.w, wd, true);
      const size_t off = rb + ((k0 >> 5) << 9) + (((k0 >> 3) & 3) << 7) + (k0 & 7);
      __builtin_nontemporal_store((unsigned)wd, (unsigned*)(P8 + off));
    }
    s = wave_sum64(s);
    if (l == 0) psq[c] = s;
  }
}

// ---- fused symmetric fp8 GEMM: LDS-DMA staged, BK=128 dbuf, permuted ----
__global__ __launch_bounds__(256, 2) void gemm_fused(
    const unsigned char* __restrict__ A, const unsigned char* __restrict__ P,
    const float* __restrict__ sq, const float* __restrict__ psq,
    unsigned* __restrict__ an_u32, unsigned* __restrict__ ap_u32,
    unsigned long long* __restrict__ pr_key, unsigned* __restrict__ cnt,
    float* __restrict__ out) {
  __shared__ __align__(16) unsigned char smem[65536];
  // staging: As[buf] = smem + buf*32768, Bs[buf] = smem + buf*32768 + 16384
  // epilogue aliases (used only after the post-K-loop barrier):
  float (*rminL)[2] = (float(*)[2])(smem);                          // 1 KB
  float (*cminL)[2] = (float(*)[2])(smem + 1024);                   // 1 KB
  float (*amaxL)[2] = (float(*)[2])(smem + 2048);                   // 1 KB
  unsigned long long (*rowkey)[2] = (unsigned long long(*)[2])(smem + 3072);
  int* lastFlag = (int*)(smem + 5120);
  float (*red2)[4] = (float(*)[4])(smem + 5376);

  const int braw = blockIdx.x;
  const int b = (braw & 7) * (NBLK / 8) + (braw >> 3);  // XCD-contiguous
  const bool isProto = b >= NSYM;
  int bi, bj;
  const unsigned char* Bmat;
  const float* sqB;
  if (!isProto) {
    // supertile decode: pairs (Si<=Sj) of 8x8-tile supertiles
    int rem = b, Si = 0, Sj = 0;
    for (;;) {
      const int cnt2 = (Si == Sj) ? 36 : 64;
      if (rem < cnt2) break;
      rem -= cnt2;
      ++Si;
      if (Si > Sj) { Si = 0; ++Sj; }
    }
    int bi_l, bj_l;
    if (Si == Sj) {
      bj_l = 0;
      while ((bj_l + 1) * (bj_l + 2) / 2 <= rem) ++bj_l;
      bi_l = rem - bj_l * (bj_l + 1) / 2;
    } else {
      bi_l = rem & 7;
      bj_l = rem >> 3;
    }
    bi = Si * 8 + bi_l;
    bj = Sj * 8 + bj_l;
    Bmat = A;
    sqB = sq;
  } else {
    const int p = b - NSYM;
    bj = p & 7;
    bi = p >> 3;
    Bmat = P;
    sqB = psq;
  }
  const int rowBase = bi * TILE;
  const int colBase = bj * TILE;
  const bool isDiag = !isProto && (bi == bj);
  const bool colSide = !isProto && (bi != bj);

  const int t = threadIdx.x;
  const int lane = t & 63;
  const int wv = t >> 6;
  const int wr = wv >> 1;
  const int wc = wv & 1;
  const int quad = lane >> 4;
  const int lc = lane & 15;

  // tile bases in permuted space: tile = 8 row-groups x 8 KB = 64 KB
  const unsigned char* gA = A + (size_t)bi * 65536;
  const unsigned char* gB = Bmat + (size_t)bj * 65536;
  const int lane16 = lane * 16;

  f32x4 acc[4][4] = {};

  // stage K-tile `it` into buffer `buf`: per wave 4 rounds x (A+B), 1 KB each
#define STAGE(buf, it)                                                      \
  {                                                                         \
    _Pragma("unroll") for (int j = 0; j < 4; ++j) {                         \
      const int idx = wv * 4 + j; /* 0..15 */                               \
      const int rg = idx >> 1, h = idx & 1;                                 \
      const int go = rg * 8192 + (it) * 2048 + h * 1024 + lane16;           \
      const int lo = (buf) * 32768 + rg * 2048 + h * 1024 + lane16;         \
      async_ld16(gA + go, smem + lo);                                       \
      async_ld16(gB + go, smem + 16384 + lo);                               \
    }                                                                       \
  }

  STAGE(0, 0);
  __syncthreads();

  int cur = 0;
#pragma unroll
  for (int it = 0; it < 4; ++it) {
    const int nxt = cur ^ 1;
    if (it < 3) STAGE(nxt, it + 1);
    const unsigned char* Ab = smem + cur * 32768;
    const unsigned char* Bb = smem + cur * 32768 + 16384;
#pragma unroll
    for (int c = 0; c < 4; ++c) {
      long af[4], bfr[4];
#pragma unroll
      for (int x = 0; x < 4; ++x) {
        af[x]  = *(const long*)(Ab + (wr * 4 + x) * 2048 + c * 512 + lane * 8);
        bfr[x] = *(const long*)(Bb + (wc * 4 + x) * 2048 + c * 512 + lane * 8);
      }
#pragma unroll
      for (int x = 0; x < 4; ++x)
#pragma unroll
        for (int y = 0; y < 4; ++y)
          acc[x][y] = __builtin_amdgcn_mfma_f32_16x16x32_fp8_fp8(
              af[x], bfr[y], acc[x][y], 0, 0, 0);
    }
    __syncthreads();  // publishes buf[nxt]; all reads of buf[cur] done
    cur = nxt;
  }
  // after final barrier: all waves done with staging LDS -> aliases are safe

  // ---- epilogue. C/D layout: col=lane&15, row=quad*4+reg ----
  float sb[4];
#pragma unroll
  for (int y = 0; y < 4; ++y) sb[y] = sqB[colBase + wc * 64 + y * 16 + lc];

  const float INF = __int_as_float(0x7f800000);

  if (!isProto) {
#pragma unroll
    for (int x = 0; x < 4; ++x) {
#pragma unroll
      for (int r = 0; r < 4; ++r) {
        const int rloc = wr * 64 + x * 16 + quad * 4 + r;
        float mv = INF, mx = -INF;
#pragma unroll
        for (int y = 0; y < 4; ++y) {
          const float v = fmaf(-2.f, acc[x][y][r], sb[y]);
          if (isDiag) {
            const int col = colBase + wc * 64 + y * 16 + lc;
            const bool same = ((rowBase + rloc) >> 3) == (col >> 3);
            mv = fminf(mv, same ? INF : v);
            mx = fmaxf(mx, same ? v : -INF);
          } else {
            mv = fminf(mv, v);
          }
        }
#pragma unroll
        for (int s = 1; s < 16; s <<= 1) mv = fminf(mv, __shfl_xor(mv, s, 64));
        if (isDiag) {
#pragma unroll
          for (int s = 1; s < 16; s <<= 1) mx = fmaxf(mx, __shfl_xor(mx, s, 64));
        }
        if (lc == 0) {
          rminL[rloc][wc] = mv;
          if (isDiag) amaxL[rloc][wc] = mx;
        }
      }
    }
    if (colSide) {
      float sa[4][4];
#pragma unroll
      for (int x = 0; x < 4; ++x)
#pragma unroll
        for (int r = 0; r < 4; ++r)
          sa[x][r] = sq[rowBase + wr * 64 + x * 16 + quad * 4 + r];
#pragma unroll
      for (int y = 0; y < 4; ++y) {
        float cv = INF;
#pragma unroll
        for (int x = 0; x < 4; ++x)
#pragma unroll
          for (int r = 0; r < 4; ++r)
            cv = fminf(cv, fmaf(-2.f, acc[x][y][r], sa[x][r]));
#pragma unroll
        for (int s = 16; s < 64; s <<= 1) cv = fminf(cv, __shfl_xor(cv, s, 64));
        if (quad == 0) cminL[wc * 64 + y * 16 + lc][wr] = cv;
      }
    }
  } else {
    // proto path: need argmin index -> u64 keys + 16-lane butterfly
#pragma unroll
    for (int x = 0; x < 4; ++x) {
      unsigned long long kmin[4] = {~0ull, ~0ull, ~0ull, ~0ull};
#pragma unroll
      for (int y = 0; y < 4; ++y) {
        const int col = colBase + wc * 64 + y * 16 + lc;
#pragma unroll
        for (int r = 0; r < 4; ++r) {
          const float v = fmaf(-2.f, acc[x][y][r], sb[y]);
          const unsigned long long kn =
              ((unsigned long long)f2o(v) << 32) | (unsigned)col;
          if (kn < kmin[r]) kmin[r] = kn;
        }
      }
#pragma unroll
      for (int r = 0; r < 4; ++r) {
#pragma unroll
        for (int s = 1; s < 16; s <<= 1) {
          const unsigned long long o = __shfl_xor(kmin[r], s, 64);
          if (o < kmin[r]) kmin[r] = o;
        }
      }
      if (lc == 0) {
#pragma unroll
        for (int r = 0; r < 4; ++r)
          rowkey[wr * 64 + x * 16 + quad * 4 + r][wc] = kmin[r];
      }
    }
  }

  __syncthreads();
  if (isProto) {
    if (t < TILE) {
      unsigned long long a = rowkey[t][0];
      const unsigned long long c = rowkey[t][1];
      if (c < a) a = c;
      atomicMin(pr_key + rowBase + t, a);
    }
  } else {
    if (t < TILE) {
      atomicMin(an_u32 + rowBase + t, f2o(fminf(rminL[t][0], rminL[t][1])));
    } else if (t < 2 * TILE) {
      const int i = t - TILE;
      if (colSide)
        atomicMin(an_u32 + colBase + i, f2o(fminf(cminL[i][0], cminL[i][1])));
      else if (isDiag)
        atomicMax(ap_u32 + rowBase + i, f2o(fmaxf(amaxL[i][0], amaxL[i][1])));
    }
  }

  // ---- last-block finalize (saves one kernel dispatch) ----
  __syncthreads();  // drains this block's global atomics before counting
  if (t == 0) {
    __threadfence();
    *lastFlag = (atomicAdd(cnt, 1u) == NBLK - 1) ? 1 : 0;
  }
  __syncthreads();
  if (*lastFlag) {
    __threadfence();
    float loss = 0.f, sp = 0.f, sn = 0.f, accv = 0.f;
#pragma unroll 8
    for (int i = t; i < NTOT; i += 256) {
      const float s = sq[i];
      const float ap = sqrtf(fmaxf(s + o2f(dev_load_u32(ap_u32 + i)), 1e-12f));
      const float an = sqrtf(fmaxf(s + o2f(dev_load_u32(an_u32 + i)), 1e-12f));
      loss += fmaxf(ap - an + MARGINV, 0.f);
      sp += ap;
      sn += an;
      accv += ((unsigned)(dev_load_u64(pr_key + i) & 0xffffffffu) ==
               (unsigned)(i >> 3)) ? 1.f : 0.f;
    }
    loss = wave_sum64(loss);
    sp = wave_sum64(sp);
    sn = wave_sum64(sn);
    accv = wave_sum64(accv);
    if (lane == 0) {
      red2[wv][0] = loss; red2[wv][1] = accv; red2[wv][2] = sp; red2[wv][3] = sn;
    }
    __syncthreads();
    if (t == 0) {
      float L = 0, Ac = 0, Pm = 0, Nn = 0;
#pragma unroll
      for (int i = 0; i < 4; ++i) {
        L += red2[i][0]; Ac += red2[i][1]; Pm += red2[i][2]; Nn += red2[i][3];
      }
      out[0] = L / NTOT;   // W = 1.0
      out[1] = Ac / NTOT;
      out[2] = Pm / NTOT;
      out[3] = Nn / NTOT;
    }
  }
}

extern "C" void kernel_launch(void* const* d_in, const int* in_sizes, int n_in,
                              void* d_out, int out_size, void* d_ws, size_t ws_size,
                              hipStream_t stream) {
  const float* inputs = (const float*)d_in[0];
  float* out = (float*)d_out;
  char* w = (char*)d_ws;
  float* sq  = (float*)(w);                                       // 32 KB
  float* psq = (float*)(w + 32768);                               // 4 KB
  unsigned* an_u32 = (unsigned*)(w + 36864);                      // 32 KB
  unsigned* ap_u32 = (unsigned*)(w + 69632);                      // 32 KB
  unsigned long long* pr_key = (unsigned long long*)(w + 102400); // 64 KB
  unsigned* cnt = (unsigned*)(w + 167936);                        // 4 B
  unsigned char* A8 = (unsigned char*)(w + 168192);               // 4 MB (permuted)
  unsigned char* P8 = (unsigned char*)(w + 168192 + (size_t)NTOT * DIM);

  prep<<<NTOT / 4 + NWAYS / 4, 256, 0, stream>>>(inputs, sq, psq, A8, P8,
                                                 an_u32, ap_u32, pr_key, cnt);
  gemm_fused<<<NBLK, 256, 0, stream>>>(A8, P8, sq, psq,
                                       an_u32, ap_u32, pr_key, cnt, out);
}

// Round 9
// 160.770 us; speedup vs baseline: 1.5250x; 1.0665x over previous
//
#include <hip/hip_runtime.h>
#include <hip/hip_bf16.h>
#include <stdint.h>

#define NTOT  8192
#define DIM   512
#define NI    8
#define NWAYS 1024
#define TILE  128
#define NSYM  2080   /* 64*65/2 upper-triangle tile pairs */
#define NBLK  2592   /* NSYM + 512 proto blocks = 8 * 324 */
#define MARGINV 0.3f

typedef float f32x4 __attribute__((ext_vector_type(4)));

// order-preserving float<->uint map (monotonic for all finite floats +/- inf)
__device__ __forceinline__ unsigned f2o(float f) {
  unsigned u = __float_as_uint(f);
  return (u & 0x80000000u) ? ~u : (u | 0x80000000u);
}
__device__ __forceinline__ float o2f(unsigned u) {
  u = (u & 0x80000000u) ? (u & 0x7fffffffu) : ~u;
  return __uint_as_float(u);
}

__device__ __forceinline__ float wave_sum64(float v) {
#pragma unroll
  for (int s = 32; s; s >>= 1) v += __shfl_xor(v, s, 64);
  return v;
}

__device__ __forceinline__ unsigned dev_load_u32(const unsigned* p) {
  return __hip_atomic_load(p, __ATOMIC_RELAXED, __HIP_MEMORY_SCOPE_AGENT);
}
__device__ __forceinline__ unsigned long long dev_load_u64(
    const unsigned long long* p) {
  return __hip_atomic_load(p, __ATOMIC_RELAXED, __HIP_MEMORY_SCOPE_AGENT);
}

__device__ __forceinline__ void async_ld16(const void* g, const void* l) {
  __builtin_amdgcn_global_load_lds(
      (__attribute__((address_space(1))) void*)(uintptr_t)g,
      (__attribute__((address_space(3))) void*)(uintptr_t)l, 16, 0, 0);
}

// Fragment-native permuted fp8 layout:
//   off(row,k) = (row>>4)*8192 + (k>>5)*512 + ((k>>3)&3)*128 + (row&15)*8 + (k&7)
// One MFMA fragment (16 rows x 32 k) = 512 contiguous bytes; lane reads at
// base + lane*8. A 128x512 tile = 8 row-groups x 8 KB contiguous = 64 KB.

// ---- prep: one wave per 8 consecutive rows; coalesced permuted stores ----
// lane: row = r0 + (l&7), k-chunk c = l>>3 (8 fp8 per (lane,kb) -> u64 store).
__global__ __launch_bounds__(256) void prep(
    const float* __restrict__ A, float* __restrict__ sq,
    float* __restrict__ psq, unsigned char* __restrict__ A8,
    unsigned char* __restrict__ P8,
    unsigned* __restrict__ an_u32, unsigned* __restrict__ ap_u32,
    unsigned long long* __restrict__ pr_key, unsigned* __restrict__ cnt) {
  if (blockIdx.x == 0 && threadIdx.x == 0) *cnt = 0;
  const int wv = threadIdx.x >> 6;
  const int l = threadIdx.x & 63;
  const int b = blockIdx.x;
  const int c = l >> 3;       // k-chunk 0..7
  const int rsub = l & 7;     // row within 8-row group
  const float4* Af4 = (const float4*)A;

  if (b < NTOT / (8 * 4)) {  // 256 blocks: rows
    const int r0 = (b * 4 + wv) * 8;
    const int row = r0 + rsub;
    float s = 0.f;
#pragma unroll
    for (int kb = 0; kb < 8; ++kb) {
      const int fi = row * 128 + kb * 16 + c * 2;
      const float4 v0 = Af4[fi];
      const float4 v1 = Af4[fi + 1];
      s = fmaf(v0.x, v0.x, fmaf(v0.y, v0.y, fmaf(v0.z, v0.z, fmaf(v0.w, v0.w, s))));
      s = fmaf(v1.x, v1.x, fmaf(v1.y, v1.y, fmaf(v1.z, v1.z, fmaf(v1.w, v1.w, s))));
      int w0 = 0, w1 = 0;
      w0 = __builtin_amdgcn_cvt_pk_fp8_f32(v0.x, v0.y, w0, false);
      w0 = __builtin_amdgcn_cvt_pk_fp8_f32(v0.z, v0.w, w0, true);
      w1 = __builtin_amdgcn_cvt_pk_fp8_f32(v1.x, v1.y, w1, false);
      w1 = __builtin_amdgcn_cvt_pk_fp8_f32(v1.z, v1.w, w1, true);
      const unsigned long long pk =
          ((unsigned long long)(unsigned)w1 << 32) | (unsigned)w0;
      const size_t off = ((size_t)(r0 >> 4) << 13) + (kb * 2 + (c >> 2)) * 512 +
                         (c & 3) * 128 + ((r0 & 8) + rsub) * 8;
      *(unsigned long long*)(A8 + off) = pk;
    }
    // sum over the 8 lanes sharing this row (stride 8)
    s += __shfl_xor(s, 8, 64);
    s += __shfl_xor(s, 16, 64);
    s += __shfl_xor(s, 32, 64);
    if (l < 8) {
      sq[r0 + l] = s;
      an_u32[r0 + l] = ~0u;
      ap_u32[r0 + l] = 0u;
      pr_key[r0 + l] = ~0ull;
    }
  } else {  // 32 blocks: prototypes (8 protos per wave)
    const int p0 = ((b - NTOT / 32) * 4 + wv) * 8;
    const int proto = p0 + rsub;
    float s = 0.f;
#pragma unroll
    for (int kb = 0; kb < 8; ++kb) {
      float4 a0 = {0.f, 0.f, 0.f, 0.f}, a1 = {0.f, 0.f, 0.f, 0.f};
#pragma unroll
      for (int j = 0; j < NI; ++j) {
        const int fi = (proto * NI + j) * 128 + kb * 16 + c * 2;
        const float4 v0 = Af4[fi];
        const float4 v1 = Af4[fi + 1];
        a0.x += v0.x; a0.y += v0.y; a0.z += v0.z; a0.w += v0.w;
        a1.x += v1.x; a1.y += v1.y; a1.z += v1.z; a1.w += v1.w;
      }
      a0.x *= (1.f / NI); a0.y *= (1.f / NI); a0.z *= (1.f / NI); a0.w *= (1.f / NI);
      a1.x *= (1.f / NI); a1.y *= (1.f / NI); a1.z *= (1.f / NI); a1.w *= (1.f / NI);
      s = fmaf(a0.x, a0.x, fmaf(a0.y, a0.y, fmaf(a0.z, a0.z, fmaf(a0.w, a0.w, s))));
      s = fmaf(a1.x, a1.x, fmaf(a1.y, a1.y, fmaf(a1.z, a1.z, fmaf(a1.w, a1.w, s))));
      int w0 = 0, w1 = 0;
      w0 = __builtin_amdgcn_cvt_pk_fp8_f32(a0.x, a0.y, w0, false);
      w0 = __builtin_amdgcn_cvt_pk_fp8_f32(a0.z, a0.w, w0, true);
      w1 = __builtin_amdgcn_cvt_pk_fp8_f32(a1.x, a1.y, w1, false);
      w1 = __builtin_amdgcn_cvt_pk_fp8_f32(a1.z, a1.w, w1, true);
      const unsigned long long pk =
          ((unsigned long long)(unsigned)w1 << 32) | (unsigned)w0;
      const size_t off = ((size_t)(p0 >> 4) << 13) + (kb * 2 + (c >> 2)) * 512 +
                         (c & 3) * 128 + ((p0 & 8) + rsub) * 8;
      *(unsigned long long*)(P8 + off) = pk;
    }
    s += __shfl_xor(s, 8, 64);
    s += __shfl_xor(s, 16, 64);
    s += __shfl_xor(s, 32, 64);
    if (l < 8) psq[p0 + l] = s;
  }
}

// ---- fused symmetric fp8 GEMM: LDS-DMA, BK=64 dbuf (32 KB), 4 blocks/CU ----
__global__ __launch_bounds__(256, 4) void gemm_fused(
    const unsigned char* __restrict__ A, const unsigned char* __restrict__ P,
    const float* __restrict__ sq, const float* __restrict__ psq,
    unsigned* __restrict__ an_u32, unsigned* __restrict__ ap_u32,
    unsigned long long* __restrict__ pr_key, unsigned* __restrict__ cnt,
    float* __restrict__ out) {
  __shared__ __align__(16) unsigned char smem[32768];
  // staging: buf at smem + buf*16384; A at +0, B at +8192 (8 KB each)
  // epilogue aliases (used only after the post-K-loop barrier):
  float (*rminL)[2] = (float(*)[2])(smem);                          // 1 KB
  float (*cminL)[2] = (float(*)[2])(smem + 1024);                   // 1 KB
  float (*amaxL)[2] = (float(*)[2])(smem + 2048);                   // 1 KB
  unsigned long long (*rowkey)[2] = (unsigned long long(*)[2])(smem + 3072);
  int* lastFlag = (int*)(smem + 5120);
  float (*red2)[4] = (float(*)[4])(smem + 5376);

  const int braw = blockIdx.x;
  const int b = (braw & 7) * (NBLK / 8) + (braw >> 3);  // XCD-contiguous
  const bool isProto = b >= NSYM;
  int bi, bj;
  const unsigned char* Bmat;
  const float* sqB;
  if (!isProto) {
    // supertile decode: pairs (Si<=Sj) of 8x8-tile supertiles
    int rem = b, Si = 0, Sj = 0;
    for (;;) {
      const int cnt2 = (Si == Sj) ? 36 : 64;
      if (rem < cnt2) break;
      rem -= cnt2;
      ++Si;
      if (Si > Sj) { Si = 0; ++Sj; }
    }
    int bi_l, bj_l;
    if (Si == Sj) {
      bj_l = 0;
      while ((bj_l + 1) * (bj_l + 2) / 2 <= rem) ++bj_l;
      bi_l = rem - bj_l * (bj_l + 1) / 2;
    } else {
      bi_l = rem & 7;
      bj_l = rem >> 3;
    }
    bi = Si * 8 + bi_l;
    bj = Sj * 8 + bj_l;
    Bmat = A;
    sqB = sq;
  } else {
    const int p = b - NSYM;
    bj = p & 7;
    bi = p >> 3;
    Bmat = P;
    sqB = psq;
  }
  const int rowBase = bi * TILE;
  const int colBase = bj * TILE;
  const bool isDiag = !isProto && (bi == bj);
  const bool colSide = !isProto && (bi != bj);

  const int t = threadIdx.x;
  const int lane = t & 63;
  const int wv = t >> 6;
  const int wr = wv >> 1;
  const int wc = wv & 1;
  const int quad = lane >> 4;
  const int lc = lane & 15;

  const unsigned char* gA = A + (size_t)bi * 65536;
  const unsigned char* gB = Bmat + (size_t)bj * 65536;
  const int lane16 = lane * 16;

  f32x4 acc[4][4] = {};

  // stage K-tile `it` (k = it*64..+63) into buffer `buf`:
  // 16 slabs of 1 KB (8 row-groups x {A,B}); 4 per wave.
#define STAGE(buf, it)                                                      \
  {                                                                         \
    _Pragma("unroll") for (int j = 0; j < 4; ++j) {                         \
      const int idx = wv * 4 + j; /* 0..15 */                               \
      const int rg = idx >> 1, mat = idx & 1;                               \
      const unsigned char* src = (mat ? gB : gA) + rg * 8192 + (it)*1024;   \
      async_ld16(src + lane16,                                              \
                 smem + (buf)*16384 + mat * 8192 + rg * 1024 + lane16);     \
    }                                                                       \
  }

  STAGE(0, 0);
  __syncthreads();

  int cur = 0;
#pragma unroll
  for (int it = 0; it < 8; ++it) {
    const int nxt = cur ^ 1;
    if (it < 7) STAGE(nxt, it + 1);
    const unsigned char* Ab = smem + cur * 16384;
    const unsigned char* Bb = smem + cur * 16384 + 8192;
#pragma unroll
    for (int c = 0; c < 2; ++c) {
      long af[4], bfr[4];
#pragma unroll
      for (int x = 0; x < 4; ++x) {
        af[x]  = *(const long*)(Ab + (wr * 4 + x) * 1024 + c * 512 + lane * 8);
        bfr[x] = *(const long*)(Bb + (wc * 4 + x) * 1024 + c * 512 + lane * 8);
      }
#pragma unroll
      for (int x = 0; x < 4; ++x)
#pragma unroll
        for (int y = 0; y < 4; ++y)
          acc[x][y] = __builtin_amdgcn_mfma_f32_16x16x32_fp8_fp8(
              af[x], bfr[y], acc[x][y], 0, 0, 0);
    }
    __syncthreads();  // publishes buf[nxt]; all reads of buf[cur] done
    cur = nxt;
  }
  // after final barrier: staging LDS free -> epilogue aliases are safe

  // ---- epilogue. C/D layout: col=lane&15, row=quad*4+reg ----
  float sb[4];
#pragma unroll
  for (int y = 0; y < 4; ++y) sb[y] = sqB[colBase + wc * 64 + y * 16 + lc];

  const float INF = __int_as_float(0x7f800000);

  if (!isProto) {
#pragma unroll
    for (int x = 0; x < 4; ++x) {
#pragma unroll
      for (int r = 0; r < 4; ++r) {
        const int rloc = wr * 64 + x * 16 + quad * 4 + r;
        float mv = INF, mx = -INF;
#pragma unroll
        for (int y = 0; y < 4; ++y) {
          const float v = fmaf(-2.f, acc[x][y][r], sb[y]);
          if (isDiag) {
            const int col = colBase + wc * 64 + y * 16 + lc;
            const bool same = ((rowBase + rloc) >> 3) == (col >> 3);
            mv = fminf(mv, same ? INF : v);
            mx = fmaxf(mx, same ? v : -INF);
          } else {
            mv = fminf(mv, v);
          }
        }
#pragma unroll
        for (int s = 1; s < 16; s <<= 1) mv = fminf(mv, __shfl_xor(mv, s, 64));
        if (isDiag) {
#pragma unroll
          for (int s = 1; s < 16; s <<= 1) mx = fmaxf(mx, __shfl_xor(mx, s, 64));
        }
        if (lc == 0) {
          rminL[rloc][wc] = mv;
          if (isDiag) amaxL[rloc][wc] = mx;
        }
      }
    }
    if (colSide) {
      float sa[4][4];
#pragma unroll
      for (int x = 0; x < 4; ++x)
#pragma unroll
        for (int r = 0; r < 4; ++r)
          sa[x][r] = sq[rowBase + wr * 64 + x * 16 + quad * 4 + r];
#pragma unroll
      for (int y = 0; y < 4; ++y) {
        float cv = INF;
#pragma unroll
        for (int x = 0; x < 4; ++x)
#pragma unroll
          for (int r = 0; r < 4; ++r)
            cv = fminf(cv, fmaf(-2.f, acc[x][y][r], sa[x][r]));
#pragma unroll
        for (int s = 16; s < 64; s <<= 1) cv = fminf(cv, __shfl_xor(cv, s, 64));
        if (quad == 0) cminL[wc * 64 + y * 16 + lc][wr] = cv;
      }
    }
  } else {
    // proto path: need argmin index -> u64 keys + 16-lane butterfly
#pragma unroll
    for (int x = 0; x < 4; ++x) {
      unsigned long long kmin[4] = {~0ull, ~0ull, ~0ull, ~0ull};
#pragma unroll
      for (int y = 0; y < 4; ++y) {
        const int col = colBase + wc * 64 + y * 16 + lc;
#pragma unroll
        for (int r = 0; r < 4; ++r) {
          const float v = fmaf(-2.f, acc[x][y][r], sb[y]);
          const unsigned long long kn =
              ((unsigned long long)f2o(v) << 32) | (unsigned)col;
          if (kn < kmin[r]) kmin[r] = kn;
        }
      }
#pragma unroll
      for (int r = 0; r < 4; ++r) {
#pragma unroll
        for (int s = 1; s < 16; s <<= 1) {
          const unsigned long long o = __shfl_xor(kmin[r], s, 64);
          if (o < kmin[r]) kmin[r] = o;
        }
      }
      if (lc == 0) {
#pragma unroll
        for (int r = 0; r < 4; ++r)
          rowkey[wr * 64 + x * 16 + quad * 4 + r][wc] = kmin[r];
      }
    }
  }

  __syncthreads();
  if (isProto) {
    if (t < TILE) {
      unsigned long long a = rowkey[t][0];
      const unsigned long long c = rowkey[t][1];
      if (c < a) a = c;
      atomicMin(pr_key + rowBase + t, a);
    }
  } else {
    if (t < TILE) {
      atomicMin(an_u32 + rowBase + t, f2o(fminf(rminL[t][0], rminL[t][1])));
    } else if (t < 2 * TILE) {
      const int i = t - TILE;
      if (colSide)
        atomicMin(an_u32 + colBase + i, f2o(fminf(cminL[i][0], cminL[i][1])));
      else if (isDiag)
        atomicMax(ap_u32 + rowBase + i, f2o(fmaxf(amaxL[i][0], amaxL[i][1])));
    }
  }

  // ---- last-block finalize (saves one kernel dispatch) ----
  __syncthreads();  // drains this block's global atomics before counting
  if (t == 0) {
    __threadfence();
    *lastFlag = (atomicAdd(cnt, 1u) == NBLK - 1) ? 1 : 0;
  }
  __syncthreads();
  if (*lastFlag) {
    __threadfence();
    float loss = 0.f, sp = 0.f, sn = 0.f, accv = 0.f;
#pragma unroll 8
    for (int i = t; i < NTOT; i += 256) {
      const float s = sq[i];
      const float ap = sqrtf(fmaxf(s + o2f(dev_load_u32(ap_u32 + i)), 1e-12f));
      const float an = sqrtf(fmaxf(s + o2f(dev_load_u32(an_u32 + i)), 1e-12f));
      loss += fmaxf(ap - an + MARGINV, 0.f);
      sp += ap;
      sn += an;
      accv += ((unsigned)(dev_load_u64(pr_key + i) & 0xffffffffu) ==
               (unsigned)(i >> 3)) ? 1.f : 0.f;
    }
    loss = wave_sum64(loss);
    sp = wave_sum64(sp);
    sn = wave_sum64(sn);
    accv = wave_sum64(accv);
    if (lane == 0) {
      red2[wv][0] = loss; red2[wv][1] = accv; red2[wv][2] = sp; red2[wv][3] = sn;
    }
    __syncthreads();
    if (t == 0) {
      float L = 0, Ac = 0, Pm = 0, Nn = 0;
#pragma unroll
      for (int i = 0; i < 4; ++i) {
        L += red2[i][0]; Ac += red2[i][1]; Pm += red2[i][2]; Nn += red2[i][3];
      }
      out[0] = L / NTOT;   // W = 1.0
      out[1] = Ac / NTOT;
      out[2] = Pm / NTOT;
      out[3] = Nn / NTOT;
    }
  }
}

extern "C" void kernel_launch(void* const* d_in, const int* in_sizes, int n_in,
                              void* d_out, int out_size, void* d_ws, size_t ws_size,
                              hipStream_t stream) {
  const float* inputs = (const float*)d_in[0];
  float* out = (float*)d_out;
  char* w = (char*)d_ws;
  float* sq  = (float*)(w);                                       // 32 KB
  float* psq = (float*)(w + 32768);                               // 4 KB
  unsigned* an_u32 = (unsigned*)(w + 36864);                      // 32 KB
  unsigned* ap_u32 = (unsigned*)(w + 69632);                      // 32 KB
  unsigned long long* pr_key = (unsigned long long*)(w + 102400); // 64 KB
  unsigned* cnt = (unsigned*)(w + 167936);                        // 4 B
  unsigned char* A8 = (unsigned char*)(w + 168192);               // 4 MB (permuted)
  unsigned char* P8 = (unsigned char*)(w + 168192 + (size_t)NTOT * DIM);

  prep<<<NTOT / 32 + NWAYS / 32, 256, 0, stream>>>(inputs, sq, psq, A8, P8,
                                                   an_u32, ap_u32, pr_key, cnt);
  gemm_fused<<<NBLK, 256, 0, stream>>>(A8, P8, sq, psq,
                                       an_u32, ap_u32, pr_key, cnt, out);
}